// Round 1
// baseline (231.751 us; speedup 1.0000x reference)
//
#include <hip/hip_runtime.h>
#include <stdint.h>

// Linformer-style attention, MI355X gfx950.
// Pipeline (all GEMMs are C = A @ B^T, bf16 inputs, f32 accum):
//   cvt: f32 -> bf16 for I, Wq, Wk, Wv, We, Wf
//   Q   = I  @ Wq^T                    [32768,256]
//   Kt  = Wk @ I[b]^T                  [256,8192] per batch  (K^T, so later stages stay A@B^T)
//   Vt  = Wv @ I[b]^T                  [256,8192]
//   KeT = We @ Kt^T   (split-K=16, f32 atomics) [256(k),256(d)]
//   VfT = Vt @ Wf^T   (split-K=16)               [256(d),256(k)]
//   logits = (Q @ KeT^T)/16 -> bf16
//   softmax rows of 256
//   Head = P @ VfT^T -> f32 out

typedef __attribute__((ext_vector_type(8))) __bf16 bf16x8;
typedef __attribute__((ext_vector_type(4))) float f32x4;
typedef __attribute__((ext_vector_type(4))) unsigned short u16x4;

__device__ __forceinline__ unsigned short f2bf(float f) {
  unsigned int u = __float_as_uint(f);
  u += 0x7FFFu + ((u >> 16) & 1u);   // RNE
  return (unsigned short)(u >> 16);
}
__device__ __forceinline__ float bf2f(unsigned short h) {
  return __uint_as_float(((unsigned int)h) << 16);
}

__device__ __forceinline__ void gld_lds16(const void* g, void* l) {
  __builtin_amdgcn_global_load_lds((const __attribute__((address_space(1))) void*)g,
                                   (__attribute__((address_space(3))) void*)l, 16, 0, 0);
}

// OUT_MODE: 0 = f32 store, 1 = bf16 store, 2 = f32 atomicAdd (split-K)
template <int OUT_MODE>
__global__ __launch_bounds__(256) void gemm_bt(
    const unsigned short* __restrict__ A, const unsigned short* __restrict__ B,
    void* __restrict__ Cv, int M, int N, int K, int kSplit, int nsplit,
    long long sA, long long sB, long long sC, float alpha) {
  __shared__ unsigned short Alds[128 * 64];
  __shared__ unsigned short Blds[128 * 64];
  const int z = blockIdx.z;
  const int batch = z / nsplit;
  const int split = z - batch * nsplit;
  const int tid = threadIdx.x;
  const int lane = tid & 63;
  const int w = tid >> 6;
  const int wr = (w >> 1) * 64, wc = (w & 1) * 64;
  const long long brow = (long long)blockIdx.y * 128;
  const long long bcol = (long long)blockIdx.x * 128;
  const unsigned short* Ab = A + sA * batch;
  const unsigned short* Bb = B + sB * batch;

  f32x4 acc[4][4];
#pragma unroll
  for (int m = 0; m < 4; ++m)
#pragma unroll
    for (int n = 0; n < 4; ++n) acc[m][n] = f32x4{0.f, 0.f, 0.f, 0.f};

  const int soff = tid * 16;  // this thread's 16B slot within each 4KB staging round
  const int nkt = kSplit >> 6;
  const int k00 = split * kSplit;

  for (int kt = 0; kt < nkt; ++kt) {
    const int kb = k00 + (kt << 6);
    __syncthreads();  // protect LDS reuse (WAR)
#pragma unroll
    for (int r = 0; r < 4; ++r) {
      const int off = r * 4096 + soff;   // byte offset in 16KB tile
      const int row = off >> 7;          // 128B per row (64 bf16)
      const int col = (off & 127) >> 1;  // element col
      gld_lds16(Ab + (brow + row) * (long long)K + kb + col, (char*)Alds + off);
      gld_lds16(Bb + (bcol + row) * (long long)K + kb + col, (char*)Blds + off);
    }
    __syncthreads();  // compiler drains vmcnt before barrier
#pragma unroll
    for (int kk = 0; kk < 2; ++kk) {
      bf16x8 a[4], b[4];
      const int ko = kk * 32 + (lane >> 4) * 8;
#pragma unroll
      for (int m = 0; m < 4; ++m)
        a[m] = *(const bf16x8*)&Alds[(wr + m * 16 + (lane & 15)) * 64 + ko];
#pragma unroll
      for (int n = 0; n < 4; ++n)
        b[n] = *(const bf16x8*)&Blds[(wc + n * 16 + (lane & 15)) * 64 + ko];
#pragma unroll
      for (int m = 0; m < 4; ++m)
#pragma unroll
        for (int n = 0; n < 4; ++n)
          acc[m][n] = __builtin_amdgcn_mfma_f32_16x16x32_bf16(a[m], b[n], acc[m][n], 0, 0, 0);
    }
  }

  // C/D layout (m89-verified): col = lane&15, row = (lane>>4)*4 + reg
  const int r0 = (lane >> 4) * 4;
  const int c0 = lane & 15;
#pragma unroll
  for (int m = 0; m < 4; ++m) {
#pragma unroll
    for (int n = 0; n < 4; ++n) {
      const long long row = brow + wr + m * 16 + r0;
      const long long col = bcol + wc + n * 16 + c0;
#pragma unroll
      for (int j = 0; j < 4; ++j) {
        const float v = acc[m][n][j] * alpha;
        const long long idx = sC * batch + (row + j) * N + col;
        if (OUT_MODE == 0)
          ((float*)Cv)[idx] = v;
        else if (OUT_MODE == 1)
          ((unsigned short*)Cv)[idx] = f2bf(v);
        else
          atomicAdd((float*)Cv + idx, v);
      }
    }
  }
}

__global__ void cvt6(const float* s0, const float* s1, const float* s2, const float* s3,
                     const float* s4, const float* s5, unsigned short* d0, unsigned short* d1,
                     unsigned short* d2, unsigned short* d3, unsigned short* d4,
                     unsigned short* d5, int n0, int n1, int n2, int n3, int n4, int n5) {
  const float* s;
  unsigned short* d;
  int n;
  switch (blockIdx.y) {
    case 0: s = s0; d = d0; n = n0; break;
    case 1: s = s1; d = d1; n = n1; break;
    case 2: s = s2; d = d2; n = n2; break;
    case 3: s = s3; d = d3; n = n3; break;
    case 4: s = s4; d = d4; n = n4; break;
    default: s = s5; d = d5; n = n5; break;
  }
  const int nt = gridDim.x * blockDim.x;
  for (int i = blockIdx.x * blockDim.x + threadIdx.x; i < (n >> 2); i += nt) {
    f32x4 v = ((const f32x4*)s)[i];
    u16x4 o = {f2bf(v[0]), f2bf(v[1]), f2bf(v[2]), f2bf(v[3])};
    ((u16x4*)d)[i] = o;
  }
}

__global__ void cvt1(const float* __restrict__ s, unsigned short* __restrict__ d, int n4) {
  int i = blockIdx.x * blockDim.x + threadIdx.x;
  if (i < n4) {
    f32x4 v = ((const f32x4*)s)[i];
    ((u16x4*)d)[i] = u16x4{f2bf(v[0]), f2bf(v[1]), f2bf(v[2]), f2bf(v[3])};
  }
}

__global__ __launch_bounds__(256) void softmax256(const unsigned short* __restrict__ L,
                                                  unsigned short* __restrict__ P) {
  const long long row = (long long)blockIdx.x * 4 + (threadIdx.x >> 6);
  const int lane = threadIdx.x & 63;
  const u16x4 v = ((const u16x4*)(L + row * 256))[lane];
  float x0 = bf2f(v[0]), x1 = bf2f(v[1]), x2 = bf2f(v[2]), x3 = bf2f(v[3]);
  float mx = fmaxf(fmaxf(x0, x1), fmaxf(x2, x3));
#pragma unroll
  for (int d = 1; d < 64; d <<= 1) mx = fmaxf(mx, __shfl_xor(mx, d));
  float e0 = __expf(x0 - mx), e1 = __expf(x1 - mx), e2 = __expf(x2 - mx), e3 = __expf(x3 - mx);
  float sum = e0 + e1 + e2 + e3;
#pragma unroll
  for (int d = 1; d < 64; d <<= 1) sum += __shfl_xor(sum, d);
  const float inv = 1.0f / sum;
  ((u16x4*)(P + row * 256))[lane] =
      u16x4{f2bf(e0 * inv), f2bf(e1 * inv), f2bf(e2 * inv), f2bf(e3 * inv)};
}

extern "C" void kernel_launch(void* const* d_in, const int* in_sizes, int n_in, void* d_out,
                              int out_size, void* d_ws, size_t ws_size, hipStream_t stream) {
  (void)in_sizes; (void)n_in; (void)out_size; (void)ws_size;
  const float* I  = (const float*)d_in[0];
  const float* Wq = (const float*)d_in[1];
  const float* Wk = (const float*)d_in[2];
  const float* Wv = (const float*)d_in[3];
  const float* We = (const float*)d_in[4];
  const float* Wf = (const float*)d_in[5];
  float* out = (float*)d_out;
  char* ws = (char*)d_ws;

  // workspace layout (bytes); peak usage ~79 MB
  constexpr long long IBF   = 0;                  // 16 MB  (B*N x 256 bf16)
  constexpr long long WQBF  = 16777216;           // 128 KB
  constexpr long long WKBF  = WQBF + 131072;
  constexpr long long WVBF  = WKBF + 131072;
  constexpr long long WEBF  = WVBF + 131072;      // 4 MB
  constexpr long long WFBF  = WEBF + 4194304;     // 4 MB
  constexpr long long QBF   = WFBF + 4194304;     // 16 MB
  constexpr long long KTBF  = QBF + 16777216;     // 16 MB
  constexpr long long VTBF  = KTBF + 16777216;    // 16 MB
  constexpr long long KET32 = VTBF + 16777216;    // 1 MB  f32
  constexpr long long VFT32 = KET32 + 1048576;    // 1 MB  f32 (contiguous with KET32)
  constexpr long long KETBF = VFT32 + 1048576;    // 512 KB
  constexpr long long VFTBF = KETBF + 524288;     // 512 KB (contiguous)
  constexpr long long LOGBF = 0;                  // reuse IBF (dead after Vt GEMM)
  constexpr long long PBF   = KTBF;               // reuse KTBF (dead after KeT GEMM)

  auto U = [&](long long off) { return (unsigned short*)(ws + off); };

  // zero split-K accumulators (ws is poisoned 0xAA before every call)
  hipMemsetAsync(ws + KET32, 0, 2097152, stream);

  cvt6<<<dim3(256, 6, 1), 256, 0, stream>>>(I, Wq, Wk, Wv, We, Wf, U(IBF), U(WQBF), U(WKBF),
                                            U(WVBF), U(WEBF), U(WFBF), 8388608, 65536, 65536,
                                            65536, 2097152, 2097152);

  // Q = I @ Wq^T : [32768,256]
  gemm_bt<1><<<dim3(2, 256, 1), 256, 0, stream>>>(U(IBF), U(WQBF), U(QBF), 32768, 256, 256, 256,
                                                  1, 0, 0, 0, 1.f);
  // Kt[b] = Wk @ I[b]^T : [256, 8192]
  gemm_bt<1><<<dim3(64, 2, 4), 256, 0, stream>>>(U(WKBF), U(IBF), U(KTBF), 256, 8192, 256, 256,
                                                 1, 0, 2097152, 2097152, 1.f);
  // Vt[b] = Wv @ I[b]^T : [256, 8192]
  gemm_bt<1><<<dim3(64, 2, 4), 256, 0, stream>>>(U(WVBF), U(IBF), U(VTBF), 256, 8192, 256, 256,
                                                 1, 0, 2097152, 2097152, 1.f);
  // KeT[b] = We @ Kt[b]^T : [256,256], split-K=16, f32 atomics
  gemm_bt<2><<<dim3(2, 2, 64), 256, 0, stream>>>(U(WEBF), U(KTBF), (void*)(ws + KET32), 256, 256,
                                                 8192, 512, 16, 0, 2097152, 65536, 1.f);
  // VfT[b] = Vt[b] @ Wf^T : [256,256], split-K=16
  gemm_bt<2><<<dim3(2, 2, 64), 256, 0, stream>>>(U(VTBF), U(WFBF), (void*)(ws + VFT32), 256, 256,
                                                 8192, 512, 16, 2097152, 0, 65536, 1.f);
  // KeT/VfT f32 -> bf16 (two contiguous 1MB regions = 524288 f32)
  cvt1<<<dim3(512), 256, 0, stream>>>((const float*)(ws + KET32), U(KETBF), 131072);
  // logits = (Q @ KeT^T) * (1/sqrt(256)) -> bf16 [32768,256]
  gemm_bt<1><<<dim3(2, 64, 4), 256, 0, stream>>>(U(QBF), U(KETBF), U(LOGBF), 8192, 256, 256, 256,
                                                 1, 2097152, 65536, 2097152, 0.0625f);
  // row softmax over 256
  softmax256<<<dim3(8192), 256, 0, stream>>>(U(LOGBF), U(PBF));
  // Head = P @ VfT^T -> f32 out
  gemm_bt<0><<<dim3(2, 64, 4), 256, 0, stream>>>(U(PBF), U(VFTBF), out, 8192, 256, 256, 256, 1,
                                                 2097152, 65536, 2097152, 1.f);
}

// Round 2
// 206.537 us; speedup vs baseline: 1.1221x; 1.1221x over previous
//
#include <hip/hip_runtime.h>
#include <stdint.h>

// Linformer attention, MI355X gfx950 — 6-dispatch pipeline, all bf16 MFMA.
//   K1a: Q  = I @ Wq^T                      [32768,256] bf16   (f32 in-flight cvt)
//   K1b: KV = [Wk;Wv] @ I[b]^T              [4][512][8192] bf16 (rows 0-255 = Kt, 256-511 = Vt)
//   K2k: Pke[b][s] = We @ Kt[b]^T partials  (split-K 16, f32)
//   K2v: Pvf[b][s] = Vt[b] @ Wf^T partials
//   K3 : reduce 16 partials -> KeT/VfT bf16 [4][256][256] each
//   K4 : flash: S = Q@KeT^T (f32 regs) -> softmax -> P bf16 in LDS -> Head = P@VfT^T -> f32 out

typedef unsigned short u16;
typedef __attribute__((ext_vector_type(8))) __bf16 bf16x8;
typedef __attribute__((ext_vector_type(4))) float f32x4;
typedef __attribute__((ext_vector_type(4))) unsigned short u16x4;
typedef __attribute__((ext_vector_type(8))) unsigned short u16x8;

__device__ __forceinline__ u16 f2bf(float f) {
  unsigned int u = __float_as_uint(f);
  u += 0x7FFFu + ((u >> 16) & 1u);  // RNE
  return (u16)(u >> 16);
}

__device__ __forceinline__ void gld_lds16(const void* g, void* l) {
  __builtin_amdgcn_global_load_lds((const __attribute__((address_space(1))) void*)g,
                                   (__attribute__((address_space(3))) void*)l, 16, 0, 0);
}

// Stage one 128x64 bf16 tile into LDS with XOR swizzle (byte ^= (row&7)<<4).
// F32=1: read f32, convert, ds_write to swizzled dest.
// F32=0: global_load_lds (linear dest) with source-preswizzled column (rule 21).
template <int F32>
__device__ __forceinline__ void stage_tile(const char* src, long long row0, long long ld,
                                           long long kb, u16* lds, int tid) {
#pragma unroll
  for (int r = 0; r < 4; ++r) {
    const int off = r * 4096 + tid * 16;
    const int row = off >> 7;
    const int colb = off & 127;
    if constexpr (F32) {
      const float* p = (const float*)src + (row0 + row) * ld + kb + (colb >> 1);
      f32x4 v0 = *(const f32x4*)p;
      f32x4 v1 = *(const f32x4*)(p + 4);
      u16x8 o;
      o[0] = f2bf(v0[0]); o[1] = f2bf(v0[1]); o[2] = f2bf(v0[2]); o[3] = f2bf(v0[3]);
      o[4] = f2bf(v1[0]); o[5] = f2bf(v1[1]); o[6] = f2bf(v1[2]); o[7] = f2bf(v1[3]);
      *(u16x8*)((char*)lds + (off ^ ((row & 7) << 4))) = o;
    } else {
      const int colb2 = colb ^ ((row & 7) << 4);
      const u16* p = (const u16*)src + (row0 + row) * ld + kb + (colb2 >> 1);
      gld_lds16(p, (char*)lds + off);
    }
  }
}

// Generic C = A @ B^T, 128x128 tile, BK=64, 4 waves. z = batch*nsplit + split.
// OUT: 0 = f32 store, 1 = bf16 store.
template <int AF32, int BF32, int OUT>
__global__ __launch_bounds__(256) void gemm2(
    const void* __restrict__ A0, const void* __restrict__ A2, const void* __restrict__ B0,
    void* __restrict__ Cv, int lda, int ldb, int ldc, int aswapY, int nsplit, int kSplitLen,
    long long sA, long long sB, long long sC, long long sSplit, float alpha) {
  __shared__ u16 Alds[8192];
  __shared__ u16 Blds[8192];
  const int z = blockIdx.z;
  const int batch = z / nsplit;
  const int split = z - batch * nsplit;
  const int tid = threadIdx.x;
  const int lane = tid & 63;
  const int w = tid >> 6;
  const int wr = (w >> 1) * 64, wc = (w & 1) * 64;
  const int by = blockIdx.y;
  const long long brow = (long long)by * 128;
  const long long bcol = (long long)blockIdx.x * 128;

  const char* Ab;
  long long arow;
  if (by >= aswapY) { Ab = (const char*)A2; arow = (long long)(by - aswapY) * 128; }
  else              { Ab = (const char*)A0; arow = brow; }
  Ab += (long long)(AF32 ? 4 : 2) * sA * batch;
  const char* Bb = (const char*)B0 + (long long)(BF32 ? 4 : 2) * sB * batch;

  f32x4 acc[4][4];
#pragma unroll
  for (int m = 0; m < 4; ++m)
#pragma unroll
    for (int n = 0; n < 4; ++n) acc[m][n] = f32x4{0.f, 0.f, 0.f, 0.f};

  const int nkt = kSplitLen >> 6;
  const long long k00 = (long long)split * kSplitLen;

  for (int kt = 0; kt < nkt; ++kt) {
    const long long kb = k00 + ((long long)kt << 6);
    __syncthreads();
    stage_tile<AF32>(Ab, arow, lda, kb, Alds, tid);
    stage_tile<BF32>(Bb, bcol, ldb, kb, Blds, tid);
    __syncthreads();
#pragma unroll
    for (int kk = 0; kk < 2; ++kk) {
      const int ko2 = (kk * 32 + (lane >> 4) * 8) * 2;  // byte offset in row
      bf16x8 a[4], b[4];
#pragma unroll
      for (int m = 0; m < 4; ++m) {
        const int ar = wr + m * 16 + (lane & 15);
        a[m] = *(const bf16x8*)((const char*)Alds + ((ar * 128 + ko2) ^ ((ar & 7) << 4)));
      }
#pragma unroll
      for (int n = 0; n < 4; ++n) {
        const int br = wc + n * 16 + (lane & 15);
        b[n] = *(const bf16x8*)((const char*)Blds + ((br * 128 + ko2) ^ ((br & 7) << 4)));
      }
#pragma unroll
      for (int m = 0; m < 4; ++m)
#pragma unroll
        for (int n = 0; n < 4; ++n)
          acc[m][n] = __builtin_amdgcn_mfma_f32_16x16x32_bf16(a[m], b[n], acc[m][n], 0, 0, 0);
    }
  }

  const int r0 = (lane >> 4) * 4;
  const int c0 = lane & 15;
  const long long cbase = sC * batch + sSplit * split;
#pragma unroll
  for (int m = 0; m < 4; ++m) {
#pragma unroll
    for (int n = 0; n < 4; ++n) {
      const long long row = brow + wr + m * 16 + r0;
      const long long col = bcol + wc + n * 16 + c0;
#pragma unroll
      for (int j = 0; j < 4; ++j) {
        const float v = acc[m][n][j] * alpha;
        const long long idx = cbase + (row + j) * ldc + col;
        if (OUT == 0) ((float*)Cv)[idx] = v;
        else          ((u16*)Cv)[idx] = f2bf(v);
      }
    }
  }
}

// Sum 16 split-K partials -> bf16. P: [8][16][65536] f32, O: [8][65536] bf16.
__global__ __launch_bounds__(256) void reduce16(const float* __restrict__ P,
                                                u16* __restrict__ O) {
  const long long t = (long long)blockIdx.x * 256 + threadIdx.x;  // [0, 131072)
  const long long g = t >> 14;
  const long long e = (t & 16383) << 2;
  const float* p = P + g * 1048576 + e;
  f32x4 s = {0.f, 0.f, 0.f, 0.f};
#pragma unroll
  for (int i = 0; i < 16; ++i) s += *(const f32x4*)(p + i * 65536);
  u16x4 o = {f2bf(s[0]), f2bf(s[1]), f2bf(s[2]), f2bf(s[3])};
  *(u16x4*)(O + g * 65536 + e) = o;
}

// Stage a 256x64 bf16 tile (src row stride 256) into Bs, swizzled via source columns.
__device__ __forceinline__ void stage_bs(const u16* src, u16* Bs, int tid) {
#pragma unroll
  for (int r = 0; r < 8; ++r) {
    const int off = r * 4096 + tid * 16;
    const int row = off >> 7;
    const int colb = (off & 127) ^ ((row & 7) << 4);
    gld_lds16(src + row * 256 + (colb >> 1), (char*)Bs + off);
  }
}

// Flash: per block, 64 rows. S = Q@KeT^T in regs -> softmax -> P(LDS,bf16) -> Head = P@VfT^T.
__global__ __launch_bounds__(256) void flash64(const u16* __restrict__ Q,
                                               const u16* __restrict__ KeT,
                                               const u16* __restrict__ VfT,
                                               float* __restrict__ out) {
  __shared__ u16 Qs[4096];    // 64x64
  __shared__ u16 Bs[16384];   // 256x64
  __shared__ u16 Ps[16384];   // 64x256, swizzled
  const int tid = threadIdx.x;
  const int lane = tid & 63;
  const int w = tid >> 6;
  const long long R0 = (long long)blockIdx.x * 64;
  const int batch = (int)(R0 >> 13);
  const u16* KeTb = KeT + (long long)batch * 65536;
  const u16* VfTb = VfT + (long long)batch * 65536;

  f32x4 acc[16];
#pragma unroll
  for (int f = 0; f < 16; ++f) acc[f] = f32x4{0.f, 0.f, 0.f, 0.f};

  // ---- QK^T: S[64][256] ----
  for (int dc = 0; dc < 4; ++dc) {
    __syncthreads();
#pragma unroll
    for (int r = 0; r < 2; ++r) {  // Qs: 64x64
      const int off = r * 4096 + tid * 16;
      const int row = off >> 7;
      const int colb = (off & 127) ^ ((row & 7) << 4);
      gld_lds16(Q + (R0 + row) * 256 + dc * 64 + (colb >> 1), (char*)Qs + off);
    }
    stage_bs(KeTb + dc * 64, Bs, tid);
    __syncthreads();
#pragma unroll
    for (int kk = 0; kk < 2; ++kk) {
      const int ko2 = (kk * 32 + (lane >> 4) * 8) * 2;
      const int ar = w * 16 + (lane & 15);
      bf16x8 a = *(const bf16x8*)((const char*)Qs + ((ar * 128 + ko2) ^ ((ar & 7) << 4)));
#pragma unroll
      for (int f = 0; f < 16; ++f) {
        const int br = f * 16 + (lane & 15);
        bf16x8 b = *(const bf16x8*)((const char*)Bs + ((br * 128 + ko2) ^ ((br & 7) << 4)));
        acc[f] = __builtin_amdgcn_mfma_f32_16x16x32_bf16(a, b, acc[f], 0, 0, 0);
      }
    }
  }

  // ---- softmax over k (scale 1/16 folded into exp) ----
#pragma unroll
  for (int j = 0; j < 4; ++j) {
    float m = acc[0][j];
#pragma unroll
    for (int f = 1; f < 16; ++f) m = fmaxf(m, acc[f][j]);
#pragma unroll
    for (int d = 1; d < 16; d <<= 1) m = fmaxf(m, __shfl_xor(m, d));
    float s = 0.f;
#pragma unroll
    for (int f = 0; f < 16; ++f) {
      const float p = __expf((acc[f][j] - m) * 0.0625f);
      acc[f][j] = p;
      s += p;
    }
#pragma unroll
    for (int d = 1; d < 16; d <<= 1) s += __shfl_xor(s, d);
    const float inv = 1.0f / s;
#pragma unroll
    for (int f = 0; f < 16; ++f) acc[f][j] *= inv;
  }
  // write P -> LDS (bf16, swizzled)
  {
    const int rbase = w * 16 + ((lane >> 4) << 2);
#pragma unroll
    for (int f = 0; f < 16; ++f) {
      const int k = f * 16 + (lane & 15);
#pragma unroll
      for (int j = 0; j < 4; ++j) {
        const int row = rbase + j;
        *(u16*)((char*)Ps + ((row * 512 + k * 2) ^ ((row & 7) << 4))) = f2bf(acc[f][j]);
      }
    }
  }
#pragma unroll
  for (int f = 0; f < 16; ++f) acc[f] = f32x4{0.f, 0.f, 0.f, 0.f};

  // ---- PV: Head[64][256] ----
  for (int kc = 0; kc < 4; ++kc) {
    __syncthreads();  // covers Ps writes (kc==0) and Bs reuse
    stage_bs(VfTb + kc * 64, Bs, tid);
    __syncthreads();
#pragma unroll
    for (int kk = 0; kk < 2; ++kk) {
      const int ko = kk * 32 + (lane >> 4) * 8;
      const int ar = w * 16 + (lane & 15);
      const int ka = kc * 64 + ko;
      bf16x8 a = *(const bf16x8*)((const char*)Ps + ((ar * 512 + ka * 2) ^ ((ar & 7) << 4)));
      const int ko2 = ko * 2;
#pragma unroll
      for (int f = 0; f < 16; ++f) {
        const int br = f * 16 + (lane & 15);
        bf16x8 b = *(const bf16x8*)((const char*)Bs + ((br * 128 + ko2) ^ ((br & 7) << 4)));
        acc[f] = __builtin_amdgcn_mfma_f32_16x16x32_bf16(a, b, acc[f], 0, 0, 0);
      }
    }
  }

  // ---- store f32 out ----
  const int r0 = (lane >> 4) * 4;
  const int c0 = lane & 15;
#pragma unroll
  for (int f = 0; f < 16; ++f) {
    const long long col = f * 16 + c0;
#pragma unroll
    for (int j = 0; j < 4; ++j)
      out[(R0 + w * 16 + r0 + j) * 256 + col] = acc[f][j];
  }
}

extern "C" void kernel_launch(void* const* d_in, const int* in_sizes, int n_in, void* d_out,
                              int out_size, void* d_ws, size_t ws_size, hipStream_t stream) {
  (void)in_sizes; (void)n_in; (void)out_size; (void)ws_size;
  const float* I  = (const float*)d_in[0];
  const float* Wq = (const float*)d_in[1];
  const float* Wk = (const float*)d_in[2];
  const float* Wv = (const float*)d_in[3];
  const float* We = (const float*)d_in[4];
  const float* Wf = (const float*)d_in[5];
  float* out = (float*)d_out;
  char* ws = (char*)d_ws;

  // workspace (bytes)
  constexpr long long QBF  = 0;          // 16 MB  [32768][256] bf16
  constexpr long long KV   = 16777216;   // 33.5MB [4][512][8192] bf16 (Kt rows 0-255, Vt 256-511)
  constexpr long long PART = 50331648;   // 33.5MB [8][16][65536] f32
  constexpr long long KETV = 83886080;   // 1 MB   [8][65536] bf16 (KeT b0..3, VfT b0..3)

  u16* Qbf  = (u16*)(ws + QBF);
  u16* KVp  = (u16*)(ws + KV);
  float* Pp = (float*)(ws + PART);
  u16* KeTp = (u16*)(ws + KETV);
  u16* VfTp = KeTp + 4 * 65536;

  const int BIG = 1 << 30;
  // K1a: Q = I @ Wq^T
  gemm2<1, 1, 1><<<dim3(2, 256, 1), 256, 0, stream>>>(I, I, Wq, Qbf, 256, 256, 256, BIG, 1, 256,
                                                      0, 0, 0, 0, 1.f);
  // K1b: KV[b] = [Wk;Wv] @ I[b]^T
  gemm2<1, 1, 1><<<dim3(64, 4, 4), 256, 0, stream>>>(Wk, Wv, I, KVp, 256, 256, 8192, 2, 1, 256,
                                                     0, 2097152, 4194304, 0, 1.f);
  // K2k: Pke partials = We @ Kt[b]^T (split 16)
  gemm2<1, 0, 0><<<dim3(2, 2, 64), 256, 0, stream>>>(We, We, KVp, Pp, 8192, 8192, 256, BIG, 16,
                                                     512, 0, 4194304, 1048576, 65536, 1.f);
  // K2v: Pvf partials = Vt[b] @ Wf^T (split 16)
  gemm2<0, 1, 0><<<dim3(2, 2, 64), 256, 0, stream>>>(KVp + 2097152, KVp, Wf, Pp + 4 * 1048576,
                                                     8192, 8192, 256, BIG, 16, 512, 4194304, 0,
                                                     1048576, 65536, 1.f);
  // K3: reduce partials -> KeT/VfT bf16
  reduce16<<<dim3(512), 256, 0, stream>>>(Pp, KeTp);
  // K4: flash fused logits+softmax+head
  flash64<<<dim3(512), 256, 0, stream>>>(Qbf, KeTp, VfTp, out);
}